// Round 8
// baseline (21.212 us; speedup 1.0000x reference)
//
#include <hip/hip_runtime.h>
#include <hip/hip_bf16.h>
#include <math.h>

#define NN 384   // 2*B
#define BB 192   // B
#define DD 128   // feature dim
#define DONE_MAGIC 0x5A5A5A5Au

// TEMP=2.0 -> s = -dist*0.5 ; TAU=1.0 ; POS_W=0.1 ; NEG_W=1.0 ; SOFT=true
//
// denom[i,p] = Wtot_i + sum_{j: |yi-yj| < |yi-yp|} (c1_j - w_j)
// The j-set is a contiguous interval in y-sorted order; its endpoints are
// pure COUNTS (predicates depend only on the y value and are monotone in
// sorted order):  lo = 2*#{q<192: yi - y_q >= ap},  hi = 2*#{q<192: y_q - yi < ap}
// (each distinct y appears exactly twice). No sorted array, no searches.
//
// Row-pair symmetry: rows i and i+192 share the SAME y, hence identical
// sg/ap/dwt/ranks and interval counts; only w_j differs.
//
// Rank via u64 lexicographic keys: y in [0,1) is non-negative, so IEEE
// float order == unsigned bit order; key=(bits(y)<<9)|idx gives the exact
// stable-sort predicate (yq<yj) || (yq==yj && q<b) as ONE u64 compare.
//
// float4 scan carries (dv0,dv1,w0,w1); Wtot = P[NN].zw (prefix total).
//
// Completion: one relaxed 64-bit packet per worker (hi=MAGIC, lo=partial
// bits) at agent scope; fixup block polls, reduces in fixed order
// (deterministic), writes out, resets packets to 0. The one-time 0xAA
// poison has hi=0xAAAAAAAA != MAGIC, so replays start clean.

__global__ __launch_bounds__(NN) void fused_kernel(
    const float* __restrict__ emb,            // [192,2,128]
    const float* __restrict__ tgt,            // [192,1]
    unsigned long long* __restrict__ pkts,    // d_ws[0..BB) u64
    float* __restrict__ out)                  // [1]
{
    const int i = blockIdx.x;          // row pair (i, i+BB)
    const int t = threadIdx.x;         // column j
    const int lane = t & 63, wid = t >> 6;

    __shared__ float partC[NN / 64];

    if (i == BB) {
        // ---- fixup block: poll packed partial|flag, reduce, write, reset ----
        float pv = 0.f;
        if (t < BB) {
            unsigned long long pkt;
            for (;;) {
                pkt = __hip_atomic_load(&pkts[t], __ATOMIC_RELAXED,
                                        __HIP_MEMORY_SCOPE_AGENT);
                if ((unsigned)(pkt >> 32) == DONE_MAGIC) break;
                __builtin_amdgcn_s_sleep(1);
            }
            pv = __uint_as_float((unsigned)pkt);
        }
        for (int off = 32; off; off >>= 1) pv += __shfl_down(pv, off);
        if (lane == 0) partC[wid] = pv;
        __syncthreads();
        if (t == 0) {
            float ssum = 0.f;
            for (int k = 0; k < NN / 64; ++k) ssum += partC[k];
            out[0] = -ssum * (1.f / (NN * (NN - 1.f)));
        }
        if (t < BB)
            __hip_atomic_store(&pkts[t], 0ull, __ATOMIC_RELAXED,
                               __HIP_MEMORY_SCOPE_AGENT);
        return;
    }

    __shared__ float yb[BB];             // distinct targets
    __shared__ unsigned long long kb[BB];// (bits(y)<<9)|idx sort keys
    __shared__ float ziS[2 * DD];        // zi0 | zi1 (contiguous in emb)
    __shared__ float4 dsort[NN];         // (dv0,dv1,w0,w1) sorted order
    __shared__ float4 P[NN + 1];         // exclusive prefix sums
    __shared__ float4 wavesum[NN / 64];

    if (t < BB) {
        const float y = tgt[t];
        yb[t] = y;
        kb[t] = ((unsigned long long)__float_as_uint(y) << 9) | (unsigned)t;
    }
    if (t < 2 * DD) ziS[t] = emb[i * 2 * DD + t];   // rows i and i+BB
    __syncthreads();

    const int b = (t < BB) ? t : t - BB;
    const float yj = yb[b];
    const unsigned long long kj =
        ((unsigned long long)__float_as_uint(yj) << 9) | (unsigned)b;
    const float yi = yb[i];              // same for both rows of the pair
    const float sg = yi - yj;            // bitwise == reference
    const float ap = fabsf(sg);

    // ---- fused: distances to BOTH rows + rank count + interval counts
    //      (compares hide under the global-load latency) ----
    const int joff = (t < BB) ? t * 2 * DD : ((t - BB) * 2 + 1) * DD;
    const float4* zj4 = reinterpret_cast<const float4*>(emb + joff);
    const float4* z04 = reinterpret_cast<const float4*>(ziS);
    const float4* z14 = reinterpret_cast<const float4*>(ziS + DD);
    float sq0 = 0.f, sq1 = 0.f;
    int cnt = 0, c_lo = 0, c_hi = 0;
#pragma unroll 4
    for (int d4 = 0; d4 < DD / 4; ++d4) {
        float4 v = zj4[d4];
        float4 u0 = z04[d4];
        float4 u1 = z14[d4];
        float a0 = u0.x - v.x, a1 = u0.y - v.y, a2 = u0.z - v.z, a3 = u0.w - v.w;
        sq0 += a0 * a0 + a1 * a1 + a2 * a2 + a3 * a3;
        float b0 = u1.x - v.x, b1 = u1.y - v.y, b2 = u1.z - v.z, b3 = u1.w - v.w;
        sq1 += b0 * b0 + b1 * b1 + b2 * b2 + b3 * b3;
#pragma unroll
        for (int e = 0; e < 6; ++e) {
            const int q = 6 * d4 + e;
            const float yq = yb[q];
            cnt  += (kb[q] < kj) ? 1 : 0;
            c_lo += (yi - yq >= ap) ? 1 : 0;   // !(yi-yq < ap), exact
            c_hi += (yq - yi < ap) ? 1 : 0;
        }
    }
    const int rk = 2 * cnt + ((t >= BB) ? 1 : 0);
    const int lo = 2 * c_lo;
    const int hi = 2 * c_hi;
    const float s0 = -((sq0 > 0.f) ? sqrtf(sq0) : 0.f) * 0.5f;
    const float s1 = -((sq1 > 0.f) ? sqrtf(sq1) : 0.f) * 0.5f;

    const float dwt = 1.f / (1.f + __expf(-ap));
    float w0 = __expf(s0) * dwt;
    float w1 = __expf(s1) * dwt;
    const float fac = (sg < 0.f) ? -0.9f : -1.0f;   // (c1-w) = fac*w
    float dv0 = fac * w0;
    float dv1 = fac * w1;
    if (t == i)      { w0 = 0.f; dv0 = 0.f; }   // diagonal of row i
    if (t == i + BB) { w1 = 0.f; dv1 = 0.f; }   // diagonal of row i+BB
    dsort[rk] = make_float4(dv0, dv1, w0, w1);
    __syncthreads();

    // ---- inclusive float4 shuffle-scan of dsort; total = Wtot in .zw ----
    float4 v = dsort[t];
    for (int off = 1; off < 64; off <<= 1) {
        float ox = __shfl_up(v.x, off);
        float oy = __shfl_up(v.y, off);
        float oz = __shfl_up(v.z, off);
        float ow = __shfl_up(v.w, off);
        if (lane >= off) { v.x += ox; v.y += oy; v.z += oz; v.w += ow; }
    }
    if (lane == 63) wavesum[wid] = v;
    __syncthreads();
    float4 base = make_float4(0.f, 0.f, 0.f, 0.f);
    for (int k = 0; k < wid; ++k) {
        base.x += wavesum[k].x; base.y += wavesum[k].y;
        base.z += wavesum[k].z; base.w += wavesum[k].w;
    }
    P[t + 1] = make_float4(base.x + v.x, base.y + v.y, base.z + v.z, base.w + v.w);
    if (t == 0) P[0] = make_float4(0.f, 0.f, 0.f, 0.f);
    __syncthreads();

    const float4 Ptot = P[NN];           // Wtot0 = .z, Wtot1 = .w
    float den0 = Ptot.z, den1 = Ptot.w;
    if (hi > lo) {
        den0 += P[hi].x - P[lo].x;
        den1 += P[hi].y - P[lo].y;
    }

    float contrib = 0.f;
    if (t != i)      contrib += s0 - __logf(den0);
    if (t != i + BB) contrib += s1 - __logf(den1);

    for (int off = 32; off; off >>= 1) contrib += __shfl_down(contrib, off);
    if (lane == 0) partC[wid] = contrib;
    __syncthreads();
    if (t == 0) {
        float ssum = 0.f;
        for (int k = 0; k < NN / 64; ++k) ssum += partC[k];
        const unsigned long long pkt =
            ((unsigned long long)DONE_MAGIC << 32) |
            (unsigned long long)__float_as_uint(ssum);
        __hip_atomic_store(&pkts[i], pkt, __ATOMIC_RELAXED,
                           __HIP_MEMORY_SCOPE_AGENT);
    }
}

extern "C" void kernel_launch(void* const* d_in, const int* in_sizes, int n_in,
                              void* d_out, int out_size, void* d_ws, size_t ws_size,
                              hipStream_t stream) {
    const float* emb = (const float*)d_in[0];
    const float* tgt = (const float*)d_in[1];
    float* out = (float*)d_out;
    unsigned long long* pkts = (unsigned long long*)d_ws;

    fused_kernel<<<BB + 1, NN, 0, stream>>>(emb, tgt, pkts, out);
}

// Round 9
// 15.924 us; speedup vs baseline: 1.3321x; 1.3321x over previous
//
#include <hip/hip_runtime.h>
#include <hip/hip_bf16.h>
#include <math.h>

#define NN 384   // 2*B
#define BB 192   // B
#define DD 128   // feature dim
#define DONE_MAGIC 0x5A5A5A5Au

// TEMP=2.0 -> s = -dist*0.5 ; TAU=1.0 ; POS_W=0.1 ; NEG_W=1.0 ; SOFT=true
//
// denom[i,p] = Wtot_i + sum_{j: |yi-yj| < |yi-yp|} (c1_j - w_j)
// The j-set is a contiguous interval in y-sorted order.
//
// Row-pair symmetry: rows i and i+192 share the SAME y, hence identical
// sg/ap/dwt/ranks/sorted-y and search intervals; only w_j differs.
//
// Rank via u64 lexicographic keys: y in [0,1) is non-negative, so IEEE
// float order == unsigned bit order; key=(bits(y)<<9)|idx gives the exact
// stable-sort predicate (yq<yj) || (yq==yj && q<b) as ONE u64 compare.
//
// Completion protocol: each worker stores ONE relaxed 64-bit packet
// (hi=DONE_MAGIC, lo=float bits of its partial) at agent scope; the
// fixup block polls packets (data travels with the flag atomically, no
// fence needed), reduces, writes out, resets packets to 0 for replay.
// The one-time 0xAA poison has hi=0xAAAAAAAA != MAGIC, so it's harmless.
//
// [R8 post-mortem] The count-based interval + float4 scan variant
// regressed 15.8 -> 21.2 us; reverted to this (round-7) structure.

__global__ __launch_bounds__(NN) void fused_kernel(
    const float* __restrict__ emb,            // [192,2,128]
    const float* __restrict__ tgt,            // [192,1]
    unsigned long long* __restrict__ pkts,    // d_ws[0..BB) u64
    float* __restrict__ out)                  // [1]
{
    const int i = blockIdx.x;          // row pair (i, i+BB)
    const int t = threadIdx.x;         // column j
    const int lane = t & 63, wid = t >> 6;

    __shared__ float partC[NN / 64];

    if (i == BB) {
        // ---- fixup block: poll packed partial|flag, reduce, write, reset ----
        float pv = 0.f;
        if (t < BB) {
            unsigned long long pkt;
            for (;;) {
                pkt = __hip_atomic_load(&pkts[t], __ATOMIC_RELAXED,
                                        __HIP_MEMORY_SCOPE_AGENT);
                if ((unsigned)(pkt >> 32) == DONE_MAGIC) break;
                __builtin_amdgcn_s_sleep(2);
            }
            pv = __uint_as_float((unsigned)pkt);
        }
        for (int off = 32; off; off >>= 1) pv += __shfl_down(pv, off);
        if (lane == 0) partC[wid] = pv;
        __syncthreads();
        if (t == 0) {
            float ssum = 0.f;
            for (int k = 0; k < NN / 64; ++k) ssum += partC[k];
            out[0] = -ssum * (1.f / (NN * (NN - 1.f)));
        }
        if (t < BB)
            __hip_atomic_store(&pkts[t], 0ull, __ATOMIC_RELAXED,
                               __HIP_MEMORY_SCOPE_AGENT);
        return;
    }

    __shared__ float yb[BB];             // distinct targets
    __shared__ unsigned long long kb[BB];// (bits(y)<<9)|idx sort keys
    __shared__ float ziS[2 * DD];        // zi0 | zi1 (contiguous in emb)
    __shared__ float ys[NN];             // y sorted
    __shared__ float2 dsort[NN];         // (c1-w) both rows, sorted order
    __shared__ float2 P[NN + 1];         // exclusive prefix sums
    __shared__ float2 wavesum[NN / 64];
    __shared__ float2 partW[NN / 64];
    __shared__ float2 wtot_sh;

    if (t < BB) {
        const float y = tgt[t];
        yb[t] = y;
        kb[t] = ((unsigned long long)__float_as_uint(y) << 9) | (unsigned)t;
    }
    if (t < 2 * DD) ziS[t] = emb[i * 2 * DD + t];   // rows i and i+BB
    __syncthreads();

    const int b = (t < BB) ? t : t - BB;
    const float yj = yb[b];
    const unsigned long long kj =
        ((unsigned long long)__float_as_uint(yj) << 9) | (unsigned)b;

    // ---- fused: distances to BOTH rows + rank count (overlaps global-load
    //      latency with the rank compares; 6 key compares per float4 chunk) ----
    const int joff = (t < BB) ? t * 2 * DD : ((t - BB) * 2 + 1) * DD;
    const float4* zj4 = reinterpret_cast<const float4*>(emb + joff);
    const float4* z04 = reinterpret_cast<const float4*>(ziS);
    const float4* z14 = reinterpret_cast<const float4*>(ziS + DD);
    float sq0 = 0.f, sq1 = 0.f;
    int cnt = 0;
#pragma unroll 4
    for (int d4 = 0; d4 < DD / 4; ++d4) {
        float4 v = zj4[d4];
        float4 u0 = z04[d4];
        float4 u1 = z14[d4];
        float a0 = u0.x - v.x, a1 = u0.y - v.y, a2 = u0.z - v.z, a3 = u0.w - v.w;
        sq0 += a0 * a0 + a1 * a1 + a2 * a2 + a3 * a3;
        float b0 = u1.x - v.x, b1 = u1.y - v.y, b2 = u1.z - v.z, b3 = u1.w - v.w;
        sq1 += b0 * b0 + b1 * b1 + b2 * b2 + b3 * b3;
        const int q = 6 * d4;
        cnt += (kb[q + 0] < kj) ? 1 : 0;
        cnt += (kb[q + 1] < kj) ? 1 : 0;
        cnt += (kb[q + 2] < kj) ? 1 : 0;
        cnt += (kb[q + 3] < kj) ? 1 : 0;
        cnt += (kb[q + 4] < kj) ? 1 : 0;
        cnt += (kb[q + 5] < kj) ? 1 : 0;
    }
    const int rk = 2 * cnt + ((t >= BB) ? 1 : 0);
    const float s0 = -((sq0 > 0.f) ? sqrtf(sq0) : 0.f) * 0.5f;
    const float s1 = -((sq1 > 0.f) ? sqrtf(sq1) : 0.f) * 0.5f;

    const float yi = yb[i];              // same for both rows of the pair
    const float sg = yi - yj;            // bitwise == reference
    const float ap = fabsf(sg);
    const float dwt = 1.f / (1.f + __expf(-ap));
    float w0 = __expf(s0) * dwt;
    float w1 = __expf(s1) * dwt;
    const float fac = (sg < 0.f) ? -0.9f : -1.0f;   // (c1-w) = fac*w
    float dv0 = fac * w0;
    float dv1 = fac * w1;
    if (t == i)      { w0 = 0.f; dv0 = 0.f; }   // diagonal of row i
    if (t == i + BB) { w1 = 0.f; dv1 = 0.f; }   // diagonal of row i+BB
    ys[rk] = yj;
    dsort[rk] = make_float2(dv0, dv1);
    __syncthreads();

    // ---- inclusive shuffle-scan of dsort + block sums of w ----
    float2 v = dsort[t];
    for (int off = 1; off < 64; off <<= 1) {
        float ox = __shfl_up(v.x, off);
        float oy = __shfl_up(v.y, off);
        if (lane >= off) { v.x += ox; v.y += oy; }
    }
    if (lane == 63) wavesum[wid] = v;
    float2 wv = make_float2(w0, w1);
    for (int off = 32; off; off >>= 1) {
        wv.x += __shfl_down(wv.x, off);
        wv.y += __shfl_down(wv.y, off);
    }
    if (lane == 0) partW[wid] = wv;
    __syncthreads();
    float2 base = make_float2(0.f, 0.f);
    for (int k = 0; k < wid; ++k) { base.x += wavesum[k].x; base.y += wavesum[k].y; }
    P[t + 1] = make_float2(base.x + v.x, base.y + v.y);
    if (t == 0) {
        P[0] = make_float2(0.f, 0.f);
        float2 W = make_float2(0.f, 0.f);
        for (int k = 0; k < NN / 64; ++k) { W.x += partW[k].x; W.y += partW[k].y; }
        wtot_sh = W;
    }
    __syncthreads();
    const float2 Wtot = wtot_sh;

    // ---- interval [lo,hi) with |yi - ys[m]| < ap  (shared by the pair) ----
    int l1 = 0, r1 = NN, l2 = 0, r2 = NN;
#pragma unroll
    for (int k = 0; k < 9; ++k) {
        if (l1 < r1) { int m = (l1 + r1) >> 1; if (yi - ys[m] < ap) r1 = m; else l1 = m + 1; }
        if (l2 < r2) { int m = (l2 + r2) >> 1; if (!(ys[m] - yi < ap)) r2 = m; else l2 = m + 1; }
    }
    const int lo = l1, hi = l2;

    float den0 = Wtot.x, den1 = Wtot.y;
    if (hi > lo) {
        den0 += P[hi].x - P[lo].x;
        den1 += P[hi].y - P[lo].y;
    }

    float contrib = 0.f;
    if (t != i)      contrib += s0 - __logf(den0);
    if (t != i + BB) contrib += s1 - __logf(den1);

    for (int off = 32; off; off >>= 1) contrib += __shfl_down(contrib, off);
    if (lane == 0) partC[wid] = contrib;
    __syncthreads();
    if (t == 0) {
        float ssum = 0.f;
        for (int k = 0; k < NN / 64; ++k) ssum += partC[k];
        const unsigned long long pkt =
            ((unsigned long long)DONE_MAGIC << 32) |
            (unsigned long long)__float_as_uint(ssum);
        __hip_atomic_store(&pkts[i], pkt, __ATOMIC_RELAXED,
                           __HIP_MEMORY_SCOPE_AGENT);
    }
}

extern "C" void kernel_launch(void* const* d_in, const int* in_sizes, int n_in,
                              void* d_out, int out_size, void* d_ws, size_t ws_size,
                              hipStream_t stream) {
    const float* emb = (const float*)d_in[0];
    const float* tgt = (const float*)d_in[1];
    float* out = (float*)d_out;
    unsigned long long* pkts = (unsigned long long*)d_ws;

    fused_kernel<<<BB + 1, NN, 0, stream>>>(emb, tgt, pkts, out);
}